// Round 5
// baseline (993.779 us; speedup 1.0000x reference)
//
#include <hip/hip_runtime.h>

// BjorckLinear: out = X @ bjorck10(W)^T
//   X: [131072, 512] f32, W: [512, 512] f32, out: [131072, 512] f32
//
// R5: (a) Bjorck = 10 launches (was 20): per-iteration strip kernel — block s
//     computes G[:,strip] = W^T W[:,strip], keeps G^T-strip in LDS, then
//     Wn[:,strip] = 1.5 W[:,strip] - 0.5 (W G)[:,strip]. No global G.
//     (b) k_big: depth-2 X register prefetch (32 KB/CU in flight -> HBM
//     saturation), W fragments direct from L2 (no LDS-W, no glds drain).

using bf16x8 = __attribute__((ext_vector_type(8))) short;
using f32x4  = __attribute__((ext_vector_type(4))) float;
using u16x8  = __attribute__((ext_vector_type(8))) unsigned short;

#define DI 512
#define GSTRIDE 528   // G^T LDS row stride (shorts): 16B-aligned, ~4-way banks

__device__ __forceinline__ unsigned short f2bf(float f) {
  unsigned int u = __builtin_bit_cast(unsigned int, f);
  u += 0x7FFFu + ((u >> 16) & 1u);   // RNE
  return (unsigned short)(u >> 16);
}
__device__ __forceinline__ float bf2f(unsigned short h) {
  unsigned int u = ((unsigned int)h) << 16;
  return __builtin_bit_cast(float, u);
}

// ---- initial split: W f32 -> f32 master + hi/lo bf16 (+ transposed) ----
__global__ void k_split(const float* __restrict__ W, float* __restrict__ Wm,
                        unsigned short* __restrict__ Wh, unsigned short* __restrict__ Wl,
                        unsigned short* __restrict__ WTh, unsigned short* __restrict__ WTl) {
  int idx = blockIdx.x * blockDim.x + threadIdx.x;
  int m = idx >> 9, i = idx & 511;
  float w = W[idx];
  Wm[idx] = w;
  unsigned short h  = f2bf(w);
  unsigned short lo = f2bf(w - bf2f(h));
  Wh[idx] = h; Wl[idx] = lo;
  WTh[i * DI + m] = h; WTl[i * DI + m] = lo;
}

// ---- one Bjorck iteration, strip-fused: 32 blocks x 512 threads ----
// block s owns output columns [16s, 16s+16).
// phase 1: G_strip = W^T W[:,strip]  (NT on WT arrays) -> G^T strip in LDS.
// phase 2: Wn_strip = 1.5 Wm_strip - 0.5 (W G)_strip; write all 5 W arrays.
__global__ __launch_bounds__(512) void k_iter(
    const unsigned short* __restrict__ WTh_c, const unsigned short* __restrict__ WTl_c,
    const unsigned short* __restrict__ Wh_c,  const unsigned short* __restrict__ Wl_c,
    const float* __restrict__ Wm_c,
    float* __restrict__ Wm_n,
    unsigned short* __restrict__ Wh_n, unsigned short* __restrict__ Wl_n,
    unsigned short* __restrict__ WTh_n, unsigned short* __restrict__ WTl_n) {
  __shared__ unsigned short GhT[16 * GSTRIDE];
  __shared__ unsigned short GlT[16 * GSTRIDE];
  const int tid = threadIdx.x;
  const int l = tid & 63, w = tid >> 6;       // 8 waves
  const int lm = l & 15, lk = l >> 4;
  const int j = (blockIdx.x << 4) + lm;       // global output column

  // ---- phase 1: G[i][j] = sum_k WT[i][k] * WT[j][k]; wave w: i in [64w,64w+64)
  {
    const int rb = j * DI + (lk << 3);
    f32x4 acc[4][3] = {};
#pragma unroll 4
    for (int k0 = 0; k0 < DI; k0 += 32) {
      bf16x8 bh = *(const bf16x8*)&WTh_c[rb + k0];
      bf16x8 bl = *(const bf16x8*)&WTl_c[rb + k0];
#pragma unroll
      for (int t = 0; t < 4; ++t) {
        const int ra = ((w << 6) + (t << 4) + lm) * DI + (lk << 3) + k0;
        bf16x8 ah = *(const bf16x8*)&WTh_c[ra];
        bf16x8 al = *(const bf16x8*)&WTl_c[ra];
        acc[t][0] = __builtin_amdgcn_mfma_f32_16x16x32_bf16(ah, bh, acc[t][0], 0, 0, 0);
        acc[t][1] = __builtin_amdgcn_mfma_f32_16x16x32_bf16(ah, bl, acc[t][1], 0, 0, 0);
        acc[t][2] = __builtin_amdgcn_mfma_f32_16x16x32_bf16(al, bh, acc[t][2], 0, 0, 0);
      }
    }
    // D[row=i_local=4*lk+r][col=j_local=lm] -> store G^T[lm][i] hi/lo
#pragma unroll
    for (int t = 0; t < 4; ++t) {
      f32x4 v4 = (acc[t][0] + acc[t][1]) + acc[t][2];
#pragma unroll
      for (int r = 0; r < 4; ++r) {
        const int i = (w << 6) + (t << 4) + (lk << 2) + r;
        const float v = v4[r];
        unsigned short h = f2bf(v);
        GhT[lm * GSTRIDE + i] = h;
        GlT[lm * GSTRIDE + i] = f2bf(v - bf2f(h));
      }
    }
  }
  __syncthreads();

  // ---- phase 2: C[m][j] = sum_k W[m][k] * G[k][j]; B from LDS (G^T strip)
  {
    f32x4 acc[4][3] = {};
#pragma unroll 4
    for (int k0 = 0; k0 < DI; k0 += 32) {
      bf16x8 bh = *(const bf16x8*)&GhT[lm * GSTRIDE + k0 + (lk << 3)];
      bf16x8 bl = *(const bf16x8*)&GlT[lm * GSTRIDE + k0 + (lk << 3)];
#pragma unroll
      for (int t = 0; t < 4; ++t) {
        const int ra = ((w << 6) + (t << 4) + lm) * DI + (lk << 3) + k0;
        bf16x8 ah = *(const bf16x8*)&Wh_c[ra];
        bf16x8 al = *(const bf16x8*)&Wl_c[ra];
        acc[t][0] = __builtin_amdgcn_mfma_f32_16x16x32_bf16(ah, bh, acc[t][0], 0, 0, 0);
        acc[t][1] = __builtin_amdgcn_mfma_f32_16x16x32_bf16(ah, bl, acc[t][1], 0, 0, 0);
        acc[t][2] = __builtin_amdgcn_mfma_f32_16x16x32_bf16(al, bh, acc[t][2], 0, 0, 0);
      }
    }
#pragma unroll
    for (int t = 0; t < 4; ++t) {
      f32x4 v4 = (acc[t][0] + acc[t][1]) + acc[t][2];
#pragma unroll
      for (int r = 0; r < 4; ++r) {
        const int m = (w << 6) + (t << 4) + (lk << 2) + r;
        const float wn = 1.5f * Wm_c[m * DI + j] - 0.5f * v4[r];
        Wm_n[m * DI + j] = wn;
        unsigned short h = f2bf(wn), lo = f2bf(wn - bf2f(h));
        Wh_n[m * DI + j] = h;   Wl_n[m * DI + j] = lo;
        WTh_n[j * DI + m] = h;  WTl_n[j * DI + m] = lo;
      }
    }
  }
}

// ---------------- big GEMM: out = bf16(X) @ Wp^T ----------------
// grid 2048, block 256 (4 waves), BM=64, BN=512 (X read once), BK=32.
// X: depth-2 register prefetch (X(k+2),X(k+3) always in flight) -> cvt ->
// swizzled LDS dbuf. W: fragments loaded directly from global (L2-resident),
// no LDS staging, no vmcnt(0) drain on the W path. Swapped MFMA operands ->
// lane holds out[gm][gn..gn+3] -> dwordx4 stores.
__global__ __launch_bounds__(256, 2) void k_big(
    const float* __restrict__ X, const unsigned short* __restrict__ Wp,
    float* __restrict__ out) {
  __shared__ unsigned short sX[2][2048];    // 64 rows x 32 k, swizzled chunks
  const int tid = threadIdx.x;
  const int w = tid >> 6, l = tid & 63;
  const int lm = l & 15, lk = l >> 4;
  const int ck = lk ^ ((lm >> 1) & 3);      // swizzled read chunk
  const int rowbase = blockIdx.x << 6;

  // X staging coords (thread t: row t>>2, chunk t&3)
  const int arow = tid >> 2, ac = tid & 3;
  const int alds = (arow * 4 + (ac ^ ((arow >> 1) & 3))) * 8;
  const float* xsrc = &X[(rowbase + arow) * DI + (ac << 3)];

  f32x4 acc[4][8] = {};
  f32x4 xv[2][2];

  // prologue: X(0) -> LDS; X(1),X(2) in flight
  {
    f32x4 t0 = *(const f32x4*)xsrc;
    f32x4 t1 = *(const f32x4*)(xsrc + 4);
    xv[0][0] = *(const f32x4*)(xsrc + 32);
    xv[0][1] = *(const f32x4*)(xsrc + 36);
    xv[1][0] = *(const f32x4*)(xsrc + 64);
    xv[1][1] = *(const f32x4*)(xsrc + 68);
    u16x8 h;
    h[0] = f2bf(t0[0]); h[1] = f2bf(t0[1]); h[2] = f2bf(t0[2]); h[3] = f2bf(t0[3]);
    h[4] = f2bf(t1[0]); h[5] = f2bf(t1[1]); h[6] = f2bf(t1[2]); h[7] = f2bf(t1[3]);
    *(u16x8*)&sX[0][alds] = h;
  }
  __syncthreads();

#pragma unroll
  for (int k = 0; k < 16; ++k) {
    const int buf = k & 1;
    // write X(k+1) (arrived 2 steps ago) into the other buffer
    if (k < 15) {
      u16x8 h;
      h[0] = f2bf(xv[buf][0][0]); h[1] = f2bf(xv[buf][0][1]);
      h[2] = f2bf(xv[buf][0][2]); h[3] = f2bf(xv[buf][0][3]);
      h[4] = f2bf(xv[buf][1][0]); h[5] = f2bf(xv[buf][1][1]);
      h[6] = f2bf(xv[buf][1][2]); h[7] = f2bf(xv[buf][1][3]);
      *(u16x8*)&sX[buf ^ 1][alds] = h;
    }
    // refill the freed slot with X(k+3)
    if (k < 13) {
      xv[buf][0] = *(const f32x4*)(xsrc + ((k + 3) << 5));
      xv[buf][1] = *(const f32x4*)(xsrc + ((k + 3) << 5) + 4);
    }
    // W fragments straight from global (L2-hot)
    bf16x8 b[8], a[4];
#pragma unroll
    for (int nf = 0; nf < 8; ++nf)
      b[nf] = *(const bf16x8*)&Wp[((w << 7) + (nf << 4) + lm) * DI + (k << 5) + (lk << 3)];
#pragma unroll
    for (int mf = 0; mf < 4; ++mf)
      a[mf] = *(const bf16x8*)&sX[buf][((mf * 16 + lm) * 4 + ck) * 8];
#pragma unroll
    for (int mf = 0; mf < 4; ++mf)
#pragma unroll
      for (int nf = 0; nf < 8; ++nf)
        acc[mf][nf] = __builtin_amdgcn_mfma_f32_16x16x32_bf16(b[nf], a[mf], acc[mf][nf], 0, 0, 0);
    __syncthreads();
  }

  // epilogue: lane holds out[gm][gn..gn+3] per (mf,nf)
#pragma unroll
  for (int mf = 0; mf < 4; ++mf) {
    const int gm = rowbase + (mf << 4) + lm;
#pragma unroll
    for (int nf = 0; nf < 8; ++nf) {
      const int gn = (w << 7) + (nf << 4) + (lk << 2);
      *(f32x4*)&out[gm * DI + gn] = acc[mf][nf];
    }
  }
}

extern "C" void kernel_launch(void* const* d_in, const int* in_sizes, int n_in,
                              void* d_out, int out_size, void* d_ws, size_t ws_size,
                              hipStream_t stream) {
  const float* X = (const float*)d_in[0];
  const float* W = (const float*)d_in[1];
  float* out = (float*)d_out;

  char* ws = (char*)d_ws;
  size_t off = 0;
  auto carve = [&](size_t bytes) { void* p = ws + off; off += (bytes + 255) & ~(size_t)255; return p; };

  const size_t F32 = (size_t)DI * DI * 4;
  const size_t BF  = (size_t)DI * DI * 2;

  float* Wm[2];           unsigned short *Wh[2], *Wl[2], *WTh[2], *WTl[2];
  Wm[0]  = (float*)carve(F32);          Wm[1]  = (float*)carve(F32);
  Wh[0]  = (unsigned short*)carve(BF);  Wh[1]  = (unsigned short*)carve(BF);
  Wl[0]  = (unsigned short*)carve(BF);  Wl[1]  = (unsigned short*)carve(BF);
  WTh[0] = (unsigned short*)carve(BF);  WTh[1] = (unsigned short*)carve(BF);
  WTl[0] = (unsigned short*)carve(BF);  WTl[1] = (unsigned short*)carve(BF);

  k_split<<<1024, 256, 0, stream>>>(W, Wm[0], Wh[0], Wl[0], WTh[0], WTl[0]);

  int cur = 0;
  for (int it = 0; it < 10; ++it) {
    const int nxt = cur ^ 1;
    k_iter<<<32, 512, 0, stream>>>(WTh[cur], WTl[cur], Wh[cur], Wl[cur], Wm[cur],
                                   Wm[nxt], Wh[nxt], Wl[nxt], WTh[nxt], WTl[nxt]);
    cur = nxt;
  }

  k_big<<<2048, 256, 0, stream>>>(X, Wh[cur], out);
}

// Round 6
// 602.586 us; speedup vs baseline: 1.6492x; 1.6492x over previous
//
#include <hip/hip_runtime.h>

// BjorckLinear: out = X @ bjorck10(W)^T
//   X: [131072, 512] f32, W: [512, 512] f32, out: [131072, 512] f32
//
// R6: (a) k_big: R4 structure + raw s_barrier with COUNTED vmcnt(2) (no full
//     drain) -> X(k+3) loads stay in flight across barriers; W glds hidden
//     under MFMA. (b) Bjorck: fused per-iteration kernel, 256 blocks
//     (8 row-chunks x 32 col-strips), G-strip computed per block (redundant
//     across row-chunks), G^T in LDS, update with 4-way K-split + LDS reduce.

using bf16x8 = __attribute__((ext_vector_type(8))) short;
using f32x4  = __attribute__((ext_vector_type(4))) float;
using u16x8  = __attribute__((ext_vector_type(8))) unsigned short;

#define DI 512
#define MFMA16(a, b, c) __builtin_amdgcn_mfma_f32_16x16x32_bf16(a, b, c, 0, 0, 0)

__device__ __forceinline__ unsigned short f2bf(float f) {
  unsigned int u = __builtin_bit_cast(unsigned int, f);
  u += 0x7FFFu + ((u >> 16) & 1u);   // RNE
  return (unsigned short)(u >> 16);
}
__device__ __forceinline__ float bf2f(unsigned short h) {
  unsigned int u = ((unsigned int)h) << 16;
  return __builtin_bit_cast(float, u);
}

// ---- initial split: W f32 -> f32 master + hi/lo bf16 (+ transposed) ----
__global__ void k_split(const float* __restrict__ W, float* __restrict__ Wm,
                        unsigned short* __restrict__ Wh, unsigned short* __restrict__ Wl,
                        unsigned short* __restrict__ WTh, unsigned short* __restrict__ WTl) {
  int idx = blockIdx.x * blockDim.x + threadIdx.x;
  int m = idx >> 9, i = idx & 511;
  float w = W[idx];
  Wm[idx] = w;
  unsigned short h  = f2bf(w);
  unsigned short lo = f2bf(w - bf2f(h));
  Wh[idx] = h; Wl[idx] = lo;
  WTh[i * DI + m] = h; WTl[i * DI + m] = lo;
}

// ---- one fused Bjorck iteration: 256 blocks (q=bx>>5 row-chunk, strip=bx&31) ----
// phase 1: G[:, strip] = W^T W[:, strip]  (full 512 rows per block, redundant
//          across q) -> G^T strip (16 x 512) hi/lo in LDS.
// phase 2: rows [64q, 64q+64): Wn = 1.5 Wm - 0.5 (W G)[:, strip]; 4-way K-split
//          across waves + LDS reduce; wave w writes frag t=w.
__global__ __launch_bounds__(256) void k_iter2(
    const unsigned short* __restrict__ WTh_c, const unsigned short* __restrict__ WTl_c,
    const unsigned short* __restrict__ Wh_c,  const unsigned short* __restrict__ Wl_c,
    const float* __restrict__ Wm_c,
    float* __restrict__ Wm_n,
    unsigned short* __restrict__ Wh_n, unsigned short* __restrict__ Wl_n,
    unsigned short* __restrict__ WTh_n, unsigned short* __restrict__ WTl_n) {
  __shared__ unsigned short GhT[16 * 520];   // G^T strip, +8 pad
  __shared__ unsigned short GlT[16 * 520];
  __shared__ f32x4 red[4][4][64];            // [src_wave][frag][lane]
  const int tid = threadIdx.x;
  const int l = tid & 63, w = tid >> 6;      // 4 waves
  const int lm = l & 15, lk = l >> 4;
  const int strip = blockIdx.x & 31, q = blockIdx.x >> 5;
  const int j0 = strip << 4;

  // ---- phase 1 ----
  {
    f32x4 acc[8][3] = {};
    const int rb = (j0 + lm) * DI + (lk << 3);
    for (int k0 = 0; k0 < DI; k0 += 32) {
      bf16x8 bh = *(const bf16x8*)&WTh_c[rb + k0];
      bf16x8 bl = *(const bf16x8*)&WTl_c[rb + k0];
#pragma unroll
      for (int t = 0; t < 8; ++t) {
        const int ra = ((w << 7) + (t << 4) + lm) * DI + k0 + (lk << 3);
        bf16x8 ah = *(const bf16x8*)&WTh_c[ra];
        bf16x8 al = *(const bf16x8*)&WTl_c[ra];
        acc[t][0] = MFMA16(ah, bh, acc[t][0]);
        acc[t][1] = MFMA16(ah, bl, acc[t][1]);
        acc[t][2] = MFMA16(al, bh, acc[t][2]);
      }
    }
#pragma unroll
    for (int t = 0; t < 8; ++t) {
      f32x4 v = (acc[t][0] + acc[t][1]) + acc[t][2];
#pragma unroll
      for (int r = 0; r < 4; ++r) {
        const int i = (w << 7) + (t << 4) + (lk << 2) + r;   // G row index
        unsigned short h = f2bf(v[r]);
        GhT[lm * 520 + i] = h;
        GlT[lm * 520 + i] = f2bf(v[r] - bf2f(h));
      }
    }
  }
  __syncthreads();

  // ---- phase 2: K-split across waves ----
  const int m0 = q << 6;
  {
    f32x4 acc2[4][3] = {};
    const int kw = w << 7;                    // wave's K range [kw, kw+128)
#pragma unroll
    for (int kk = 0; kk < 4; ++kk) {
      const int k = kw + (kk << 5);
      bf16x8 bh = *(const bf16x8*)&GhT[lm * 520 + k + (lk << 3)];
      bf16x8 bl = *(const bf16x8*)&GlT[lm * 520 + k + (lk << 3)];
#pragma unroll
      for (int t = 0; t < 4; ++t) {
        const int ra = (m0 + (t << 4) + lm) * DI + k + (lk << 3);
        bf16x8 ah = *(const bf16x8*)&Wh_c[ra];
        bf16x8 al = *(const bf16x8*)&Wl_c[ra];
        acc2[t][0] = MFMA16(ah, bh, acc2[t][0]);
        acc2[t][1] = MFMA16(ah, bl, acc2[t][1]);
        acc2[t][2] = MFMA16(al, bh, acc2[t][2]);
      }
    }
#pragma unroll
    for (int t = 0; t < 4; ++t)
      red[w][t][l] = (acc2[t][0] + acc2[t][1]) + acc2[t][2];
  }
  __syncthreads();

  // wave w finalizes frag t=w (rows m0+16w .. +16)
  {
    f32x4 v = (red[0][w][l] + red[1][w][l]) + (red[2][w][l] + red[3][w][l]);
    const int j = j0 + lm;
#pragma unroll
    for (int r = 0; r < 4; ++r) {
      const int m = m0 + (w << 4) + (lk << 2) + r;
      const float wn = 1.5f * Wm_c[m * DI + j] - 0.5f * v[r];
      Wm_n[m * DI + j] = wn;
      unsigned short h = f2bf(wn), lo = f2bf(wn - bf2f(h));
      Wh_n[m * DI + j] = h;   Wl_n[m * DI + j] = lo;
      WTh_n[j * DI + m] = h;  WTl_n[j * DI + m] = lo;
    }
  }
}

// ---------------- direct-to-LDS helper ----------------
#if defined(__has_builtin)
#if __has_builtin(__builtin_amdgcn_global_load_lds)
#define HAVE_GLDS 1
#endif
#endif

#ifdef HAVE_GLDS
__device__ __forceinline__ void gl2lds16(const unsigned short* g, unsigned short* lds) {
  __builtin_amdgcn_global_load_lds(
      (const __attribute__((address_space(1))) void*)g,
      (__attribute__((address_space(3))) void*)lds, 16, 0, 0);
}
#endif

// ---------------- big GEMM: out = bf16(X) @ Wp^T ----------------
// grid 2048, block 256 (4 waves), BM=64, BN=512 (X read once), BK=32.
// Double-buffered LDS; W via glds w16 (pre-swizzled source); X reg-staged
// depth-2. Raw s_barrier with counted vmcnt(2): X(k+3) loads stay in flight
// across barriers; glds W(k+1) published at each barrier. Swapped MFMA
// operands -> lane holds out[gm][gn..gn+3] -> dwordx4 stores.
__global__ __launch_bounds__(256, 2) void k_big(
    const float* __restrict__ X, const unsigned short* __restrict__ Wp,
    float* __restrict__ out) {
  __shared__ unsigned short sX[2][2048];
  __shared__ unsigned short sB[2][16384];
  const int tid = threadIdx.x;
  const int w = tid >> 6, l = tid & 63;
  const int lm = l & 15, lk = l >> 4;
  const int ck = lk ^ ((lm >> 1) & 3);      // swizzled read chunk
  const int rowbase = blockIdx.x << 6;

  const int arow = tid >> 2, ac = tid & 3;
  const int alds = (arow * 4 + (ac ^ ((arow >> 1) & 3))) * 8;
  const float* xsrc = &X[(rowbase + arow) * DI + (ac << 3)];

  const int brow_l = l >> 2;
  const int bcs = (l & 3) ^ ((brow_l >> 1) & 3);

  f32x4 acc[4][8] = {};
  f32x4 xv[2][2];

  auto stage_b = [&](int kk, int bb) {
#pragma unroll
    for (int ph = 0; ph < 8; ++ph) {
      const int rowblk = ph * 64 + w * 16;
      const unsigned short* src = &Wp[(rowblk + brow_l) * DI + (kk << 5) + bcs * 8];
#ifdef HAVE_GLDS
      gl2lds16(src, &sB[bb][rowblk * 32]);
#else
      u16x8 v = *(const u16x8*)src;
      *(u16x8*)&sB[bb][rowblk * 32 + l * 8] = v;
#endif
    }
  };
  auto cvt_write = [&](const f32x4& v0, const f32x4& v1, int bb) {
    u16x8 h;
    h[0] = f2bf(v0[0]); h[1] = f2bf(v0[1]); h[2] = f2bf(v0[2]); h[3] = f2bf(v0[3]);
    h[4] = f2bf(v1[0]); h[5] = f2bf(v1[1]); h[6] = f2bf(v1[2]); h[7] = f2bf(v1[3]);
    *(u16x8*)&sX[bb][alds] = h;
  };

  // prologue: stage k=0; X(1),X(2) in flight
  stage_b(0, 0);
  f32x4 t0 = *(const f32x4*)xsrc;
  f32x4 t1 = *(const f32x4*)(xsrc + 4);
  xv[0][0] = *(const f32x4*)(xsrc + 32);
  xv[0][1] = *(const f32x4*)(xsrc + 36);
  xv[1][0] = *(const f32x4*)(xsrc + 64);
  xv[1][1] = *(const f32x4*)(xsrc + 68);
  cvt_write(t0, t1, 0);
  asm volatile("s_waitcnt vmcnt(4) lgkmcnt(0)" ::: "memory");  // W(0)+X(0) done
  __builtin_amdgcn_s_barrier();
  __builtin_amdgcn_sched_barrier(0);

#pragma unroll
  for (int k = 0; k < 16; ++k) {
    const int buf = k & 1;
    if (k < 15) stage_b(k + 1, buf ^ 1);      // 8 glds into other buffer
    f32x4 n0, n1;
    if (k < 13) {                             // issue X(k+3) early
      n0 = *(const f32x4*)(xsrc + ((k + 3) << 5));
      n1 = *(const f32x4*)(xsrc + ((k + 3) << 5) + 4);
    }
    if (k < 15) cvt_write(xv[buf][0], xv[buf][1], buf ^ 1);  // X(k+1) -> LDS
    if (k < 13) { xv[buf][0] = n0; xv[buf][1] = n1; }

    bf16x8 a[4], b[8];
#pragma unroll
    for (int mf = 0; mf < 4; ++mf)
      a[mf] = *(const bf16x8*)&sX[buf][((mf * 16 + lm) * 4 + ck) * 8];
#pragma unroll
    for (int nf = 0; nf < 8; ++nf)
      b[nf] = *(const bf16x8*)&sB[buf][((w * 128 + nf * 16 + lm) * 4 + ck) * 8];
#pragma unroll
    for (int mf = 0; mf < 4; ++mf)
#pragma unroll
      for (int nf = 0; nf < 8; ++nf)
        acc[mf][nf] = MFMA16(b[nf], a[mf], acc[mf][nf]);

    if (k < 15) {
      if (k < 13)
        asm volatile("s_waitcnt vmcnt(2) lgkmcnt(0)" ::: "memory");  // X(k+3) stays in flight
      else
        asm volatile("s_waitcnt vmcnt(0) lgkmcnt(0)" ::: "memory");
      __builtin_amdgcn_s_barrier();
      __builtin_amdgcn_sched_barrier(0);
    }
  }

  // epilogue: lane holds out[gm][gn..gn+3] per (mf,nf)
#pragma unroll
  for (int mf = 0; mf < 4; ++mf) {
    const int gm = rowbase + (mf << 4) + lm;
#pragma unroll
    for (int nf = 0; nf < 8; ++nf) {
      const int gn = (w << 7) + (nf << 4) + (lk << 2);
      *(f32x4*)&out[gm * DI + gn] = acc[mf][nf];
    }
  }
}

extern "C" void kernel_launch(void* const* d_in, const int* in_sizes, int n_in,
                              void* d_out, int out_size, void* d_ws, size_t ws_size,
                              hipStream_t stream) {
  const float* X = (const float*)d_in[0];
  const float* W = (const float*)d_in[1];
  float* out = (float*)d_out;

  char* ws = (char*)d_ws;
  size_t off = 0;
  auto carve = [&](size_t bytes) { void* p = ws + off; off += (bytes + 255) & ~(size_t)255; return p; };

  const size_t F32 = (size_t)DI * DI * 4;
  const size_t BF  = (size_t)DI * DI * 2;

  float* Wm[2];           unsigned short *Wh[2], *Wl[2], *WTh[2], *WTl[2];
  Wm[0]  = (float*)carve(F32);          Wm[1]  = (float*)carve(F32);
  Wh[0]  = (unsigned short*)carve(BF);  Wh[1]  = (unsigned short*)carve(BF);
  Wl[0]  = (unsigned short*)carve(BF);  Wl[1]  = (unsigned short*)carve(BF);
  WTh[0] = (unsigned short*)carve(BF);  WTh[1] = (unsigned short*)carve(BF);
  WTl[0] = (unsigned short*)carve(BF);  WTl[1] = (unsigned short*)carve(BF);

  k_split<<<1024, 256, 0, stream>>>(W, Wm[0], Wh[0], Wl[0], WTh[0], WTl[0]);

  int cur = 0;
  for (int it = 0; it < 10; ++it) {
    const int nxt = cur ^ 1;
    k_iter2<<<256, 256, 0, stream>>>(WTh[cur], WTl[cur], Wh[cur], Wl[cur], Wm[cur],
                                     Wm[nxt], Wh[nxt], Wl[nxt], WTh[nxt], WTl[nxt]);
    cur = nxt;
  }

  k_big<<<2048, 256, 0, stream>>>(X, Wh[cur], out);
}

// Round 7
// 428.712 us; speedup vs baseline: 2.3181x; 1.4056x over previous
//
#include <hip/hip_runtime.h>

// BjorckLinear: out = X @ bjorck10(W)^T
//   X: [131072, 512] f32, W: [512, 512] f32, out: [131072, 512] f32
//
// R7: (a) Bjorck reverted to the proven 21-launch k_mm2 structure (~10us/slot);
//     (b) X->bf16 conversion hidden inside the 10 gram launches (1024 extra
//     streaming blocks per launch, ~4us BW < launch slot => free);
//     (c) k_big reads pre-converted bf16 X: HBM 524->393 MB, all staging via
//     global_load_lds w16 with both-sides chunk swizzle, 2-barrier k-loop.

using bf16x8 = __attribute__((ext_vector_type(8))) short;
using f32x4  = __attribute__((ext_vector_type(4))) float;
using u16x8  = __attribute__((ext_vector_type(8))) unsigned short;

#define DI 512
#define MFMA16(a, b, c) __builtin_amdgcn_mfma_f32_16x16x32_bf16(a, b, c, 0, 0, 0)
#define XTOT 67108864LL
#define XSLICE 6711296LL   // 10 slices cover XTOT; 8-aligned

__device__ __forceinline__ unsigned short f2bf(float f) {
  unsigned int u = __builtin_bit_cast(unsigned int, f);
  u += 0x7FFFu + ((u >> 16) & 1u);   // RNE
  return (unsigned short)(u >> 16);
}
__device__ __forceinline__ float bf2f(unsigned short h) {
  unsigned int u = ((unsigned int)h) << 16;
  return __builtin_bit_cast(float, u);
}

// ---- initial split: W f32 -> f32 master + hi/lo bf16 (+ transposed) ----
__global__ void k_split(const float* __restrict__ W, float* __restrict__ Wm,
                        unsigned short* __restrict__ Wh, unsigned short* __restrict__ Wl,
                        unsigned short* __restrict__ WTh, unsigned short* __restrict__ WTl) {
  int idx = blockIdx.x * blockDim.x + threadIdx.x;
  int m = idx >> 9, i = idx & 511;
  float w = W[idx];
  Wm[idx] = w;
  unsigned short h  = f2bf(w);
  unsigned short lo = f2bf(w - bf2f(h));
  Wh[idx] = h; Wl[idx] = lo;
  WTh[i * DI + m] = h; WTl[i * DI + m] = lo;
}

// ---- 512x512 NT GEMM: wave per (16x16 tile, K-half); LDS pair-reduce ----
// blocks >= 512: X->bf16 converter (slice `slice`), hidden under the launch.
__global__ __launch_bounds__(256) void k_mm2(
    const unsigned short* __restrict__ Ah, const unsigned short* __restrict__ Al,
    const unsigned short* __restrict__ Bh, const unsigned short* __restrict__ Bl,
    int mode,
    const float* __restrict__ Wm_in, float* __restrict__ Wm_out,
    unsigned short* __restrict__ Oh, unsigned short* __restrict__ Ol,
    unsigned short* __restrict__ OTh, unsigned short* __restrict__ OTl,
    const float* __restrict__ Xsrc, unsigned short* __restrict__ Xb, int slice) {
  const int tid = threadIdx.x;
  if (blockIdx.x >= 512) {                    // ---- X converter blocks ----
    if (Xb == nullptr) return;
    long long s0 = (long long)slice * XSLICE;
    long long send = s0 + XSLICE; if (send > XTOT) send = XTOT;
    for (long long i = s0 + ((long long)(blockIdx.x - 512) * 256 + tid) * 8;
         i < send; i += 1024LL * 256 * 8) {
      f32x4 v0 = *(const f32x4*)&Xsrc[i];
      f32x4 v1 = *(const f32x4*)&Xsrc[i + 4];
      u16x8 h;
      h[0] = f2bf(v0[0]); h[1] = f2bf(v0[1]); h[2] = f2bf(v0[2]); h[3] = f2bf(v0[3]);
      h[4] = f2bf(v1[0]); h[5] = f2bf(v1[1]); h[6] = f2bf(v1[2]); h[7] = f2bf(v1[3]);
      *(u16x8*)&Xb[i] = h;
    }
    return;
  }

  const int l = tid & 63, lw = tid >> 6;
  const int wid = (blockIdx.x << 2) | lw;     // 0..2047
  const int tile = wid >> 1, half = wid & 1;  // 1024 tiles x 2 K-halves
  const int m0 = (tile >> 5) << 4, n0 = (tile & 31) << 4;
  const int kb = half << 8;
  const int lm = l & 15, lk = l >> 4;
  const int ra = (m0 + lm) * DI + kb + (lk << 3);
  const int rb = (n0 + lm) * DI + kb + (lk << 3);

  __shared__ f32x4 red[2][64];
  const int pr = lw >> 1;

  f32x4 a0{}, a1{}, a2{}, a3{}, a4{}, a5{};
#pragma unroll
  for (int k0 = 0; k0 < 256; k0 += 64) {
    bf16x8 ah0 = *(const bf16x8*)&Ah[ra + k0];
    bf16x8 al0 = *(const bf16x8*)&Al[ra + k0];
    bf16x8 bh0 = *(const bf16x8*)&Bh[rb + k0];
    bf16x8 bl0 = *(const bf16x8*)&Bl[rb + k0];
    bf16x8 ah1 = *(const bf16x8*)&Ah[ra + k0 + 32];
    bf16x8 al1 = *(const bf16x8*)&Al[ra + k0 + 32];
    bf16x8 bh1 = *(const bf16x8*)&Bh[rb + k0 + 32];
    bf16x8 bl1 = *(const bf16x8*)&Bl[rb + k0 + 32];
    a0 = MFMA16(ah0, bh0, a0);
    a1 = MFMA16(ah0, bl0, a1);
    a2 = MFMA16(al0, bh0, a2);
    a3 = MFMA16(ah1, bh1, a3);
    a4 = MFMA16(ah1, bl1, a4);
    a5 = MFMA16(al1, bh1, a5);
  }
  f32x4 acc = (a0 + a1) + (a2 + a3) + (a4 + a5);

  if (half) red[pr][l] = acc;
  __syncthreads();
  if (!half) {
    acc += red[pr][l];
    const int r0 = m0 + (lk << 2);
    const int cn = n0 + lm;
#pragma unroll
    for (int r = 0; r < 4; ++r) {
      const int gm = r0 + r, gn = cn;
      const float v = acc[r];
      if (mode == 0) {
        unsigned short h = f2bf(v);
        Oh[gm * DI + gn] = h;
        Ol[gm * DI + gn] = f2bf(v - bf2f(h));
      } else {
        const float wn = 1.5f * Wm_in[gm * DI + gn] - 0.5f * v;
        Wm_out[gm * DI + gn] = wn;
        unsigned short h = f2bf(wn), lo = f2bf(wn - bf2f(h));
        Oh[gm * DI + gn] = h;   Ol[gm * DI + gn] = lo;
        OTh[gn * DI + gm] = h;  OTl[gn * DI + gm] = lo;
      }
    }
  }
}

// ---------------- direct-to-LDS helper ----------------
#if defined(__has_builtin)
#if __has_builtin(__builtin_amdgcn_global_load_lds)
#define HAVE_GLDS 1
#endif
#endif

#ifdef HAVE_GLDS
__device__ __forceinline__ void gl2lds16(const unsigned short* g, unsigned short* lds) {
  __builtin_amdgcn_global_load_lds(
      (const __attribute__((address_space(1))) void*)g,
      (__attribute__((address_space(3))) void*)lds, 16, 0, 0);
}
#endif

// ---------------- big GEMM (bf16 X): out = Xb @ Wp^T ----------------
// grid 2048, block 256 (4 waves), BM=64, BN=512 (X read once), BK=32.
// All staging via glds w16, pre-swizzled sources; double-buffered LDS;
// 1 X-glds + 8 W-glds per wave per k-step; one __syncthreads per k-step.
// Swapped MFMA operands -> lane holds out[gm][gn..gn+3] -> dwordx4 stores.
__global__ __launch_bounds__(256, 2) void k_big_bf(
    const unsigned short* __restrict__ Xb, const unsigned short* __restrict__ Wp,
    float* __restrict__ out) {
  __shared__ unsigned short sX[2][2048];    // 64 rows x 32 k
  __shared__ unsigned short sB[2][16384];   // 512 rows x 32 k
  const int tid = threadIdx.x;
  const int w = tid >> 6, l = tid & 63;
  const int lm = l & 15, lk = l >> 4;
  const int ck = lk ^ ((lm >> 1) & 3);          // swizzled read chunk
  const int rowbase = blockIdx.x << 6;
  const int lrow = l >> 2;                      // 0..15 (row within 16-row block)
  const int lcs = (l & 3) ^ ((lrow >> 1) & 3);  // pre-swizzled source chunk

  f32x4 acc[4][8] = {};

  auto stage = [&](int kk, int bb) {
    // X: wave w stages rows [16w, 16w+16)
    const unsigned short* xs =
        &Xb[(rowbase + (w << 4) + lrow) * DI + (kk << 5) + (lcs << 3)];
#ifdef HAVE_GLDS
    gl2lds16(xs, &sX[bb][w << 9]);
#else
    *(u16x8*)&sX[bb][(w << 9) + l * 8] = *(const u16x8*)xs;
#endif
#pragma unroll
    for (int ph = 0; ph < 8; ++ph) {
      const int rowblk = ph * 64 + w * 16;
      const unsigned short* src =
          &Wp[(rowblk + lrow) * DI + (kk << 5) + (lcs << 3)];
#ifdef HAVE_GLDS
      gl2lds16(src, &sB[bb][rowblk * 32]);
#else
      *(u16x8*)&sB[bb][rowblk * 32 + l * 8] = *(const u16x8*)src;
#endif
    }
  };

  stage(0, 0);
  __syncthreads();

  for (int k = 0; k < 16; ++k) {
    const int buf = k & 1;
    if (k < 15) stage(k + 1, buf ^ 1);
    bf16x8 a[4], b[8];
#pragma unroll
    for (int mf = 0; mf < 4; ++mf)
      a[mf] = *(const bf16x8*)&sX[buf][((mf * 16 + lm) * 4 + ck) * 8];
#pragma unroll
    for (int nf = 0; nf < 8; ++nf)
      b[nf] = *(const bf16x8*)&sB[buf][((w * 128 + nf * 16 + lm) * 4 + ck) * 8];
#pragma unroll
    for (int mf = 0; mf < 4; ++mf)
#pragma unroll
      for (int nf = 0; nf < 8; ++nf)
        acc[mf][nf] = MFMA16(b[nf], a[mf], acc[mf][nf]);
    __syncthreads();
  }

#pragma unroll
  for (int mf = 0; mf < 4; ++mf) {
    const int gm = rowbase + (mf << 4) + lm;
#pragma unroll
    for (int nf = 0; nf < 8; ++nf) {
      const int gn = (w << 7) + (nf << 4) + (lk << 2);
      *(f32x4*)&out[gm * DI + gn] = acc[mf][nf];
    }
  }
}

// ---------------- fallback big GEMM (f32 X), R6-proven ----------------
__global__ __launch_bounds__(256, 2) void k_big(
    const float* __restrict__ X, const unsigned short* __restrict__ Wp,
    float* __restrict__ out) {
  __shared__ unsigned short sX[2][2048];
  __shared__ unsigned short sB[2][16384];
  const int tid = threadIdx.x;
  const int w = tid >> 6, l = tid & 63;
  const int lm = l & 15, lk = l >> 4;
  const int ck = lk ^ ((lm >> 1) & 3);
  const int rowbase = blockIdx.x << 6;

  const int arow = tid >> 2, ac = tid & 3;
  const int alds = (arow * 4 + (ac ^ ((arow >> 1) & 3))) * 8;
  const float* xsrc = &X[(rowbase + arow) * DI + (ac << 3)];

  const int brow_l = l >> 2;
  const int bcs = (l & 3) ^ ((brow_l >> 1) & 3);

  f32x4 acc[4][8] = {};
  f32x4 xv[2];

  auto stage_b = [&](int kk, int bb) {
#pragma unroll
    for (int ph = 0; ph < 8; ++ph) {
      const int rowblk = ph * 64 + w * 16;
      const unsigned short* src = &Wp[(rowblk + brow_l) * DI + (kk << 5) + bcs * 8];
#ifdef HAVE_GLDS
      gl2lds16(src, &sB[bb][rowblk * 32]);
#else
      *(u16x8*)&sB[bb][rowblk * 32 + l * 8] = *(const u16x8*)src;
#endif
    }
  };
  auto cvt_write = [&](const f32x4& v0, const f32x4& v1, int bb) {
    u16x8 h;
    h[0] = f2bf(v0[0]); h[1] = f2bf(v0[1]); h[2] = f2bf(v0[2]); h[3] = f2bf(v0[3]);
    h[4] = f2bf(v1[0]); h[5] = f2bf(v1[1]); h[6] = f2bf(v1[2]); h[7] = f2bf(v1[3]);
    *(u16x8*)&sX[bb][alds] = h;
  };

  stage_b(0, 0);
  f32x4 t0 = *(const f32x4*)xsrc;
  f32x4 t1 = *(const f32x4*)(xsrc + 4);
  xv[0] = *(const f32x4*)(xsrc + 32);
  xv[1] = *(const f32x4*)(xsrc + 36);
  cvt_write(t0, t1, 0);
  __syncthreads();

  for (int k = 0; k < 16; ++k) {
    const int buf = k & 1;
    if (k < 15) stage_b(k + 1, buf ^ 1);
    f32x4 n0, n1;
    if (k < 14) {
      n0 = *(const f32x4*)(xsrc + ((k + 2) << 5));
      n1 = *(const f32x4*)(xsrc + ((k + 2) << 5) + 4);
    }
    if (k < 15) cvt_write(xv[0], xv[1], buf ^ 1);
    if (k < 14) { xv[0] = n0; xv[1] = n1; }

    bf16x8 a[4], b[8];
#pragma unroll
    for (int mf = 0; mf < 4; ++mf)
      a[mf] = *(const bf16x8*)&sX[buf][((mf * 16 + lm) * 4 + ck) * 8];
#pragma unroll
    for (int nf = 0; nf < 8; ++nf)
      b[nf] = *(const bf16x8*)&sB[buf][((w * 128 + nf * 16 + lm) * 4 + ck) * 8];
#pragma unroll
    for (int mf = 0; mf < 4; ++mf)
#pragma unroll
      for (int nf = 0; nf < 8; ++nf)
        acc[mf][nf] = MFMA16(b[nf], a[mf], acc[mf][nf]);
    __syncthreads();
  }

#pragma unroll
  for (int mf = 0; mf < 4; ++mf) {
    const int gm = rowbase + (mf << 4) + lm;
#pragma unroll
    for (int nf = 0; nf < 8; ++nf) {
      const int gn = (w << 7) + (nf << 4) + (lk << 2);
      *(f32x4*)&out[gm * DI + gn] = acc[mf][nf];
    }
  }
}

extern "C" void kernel_launch(void* const* d_in, const int* in_sizes, int n_in,
                              void* d_out, int out_size, void* d_ws, size_t ws_size,
                              hipStream_t stream) {
  const float* X = (const float*)d_in[0];
  const float* W = (const float*)d_in[1];
  float* out = (float*)d_out;

  char* ws = (char*)d_ws;
  size_t off = 0;
  auto carve = [&](size_t bytes) { void* p = ws + off; off += (bytes + 255) & ~(size_t)255; return p; };

  const size_t F32 = (size_t)DI * DI * 4;
  const size_t BF  = (size_t)DI * DI * 2;

  float* Wm[2];           unsigned short *Wh[2], *Wl[2], *WTh[2], *WTl[2];
  Wm[0]  = (float*)carve(F32);          Wm[1]  = (float*)carve(F32);
  Wh[0]  = (unsigned short*)carve(BF);  Wh[1]  = (unsigned short*)carve(BF);
  Wl[0]  = (unsigned short*)carve(BF);  Wl[1]  = (unsigned short*)carve(BF);
  WTh[0] = (unsigned short*)carve(BF);  WTh[1] = (unsigned short*)carve(BF);
  WTl[0] = (unsigned short*)carve(BF);  WTl[1] = (unsigned short*)carve(BF);
  unsigned short* Gh = (unsigned short*)carve(BF);
  unsigned short* Gl = (unsigned short*)carve(BF);

  // X bf16 buffer (134.2 MB) — only if workspace allows
  const size_t XB_BYTES = (size_t)XTOT * 2;
  unsigned short* Xb = nullptr;
  if (off + XB_BYTES <= ws_size) Xb = (unsigned short*)carve(XB_BYTES);

  k_split<<<1024, 256, 0, stream>>>(W, Wm[0], Wh[0], Wl[0], WTh[0], WTl[0]);

  int cur = 0;
  for (int it = 0; it < 10; ++it) {
    // G = W^T W  (+ hidden X->bf16 conversion slice `it`)
    k_mm2<<<Xb ? 1536 : 512, 256, 0, stream>>>(
        WTh[cur], WTl[cur], WTh[cur], WTl[cur], 0,
        nullptr, nullptr, Gh, Gl, nullptr, nullptr,
        X, Xb, it);
    const int nxt = cur ^ 1;
    // Wnew = 1.5 W - 0.5 W G   (G symmetric)
    k_mm2<<<512, 256, 0, stream>>>(
        Wh[cur], Wl[cur], Gh, Gl, 1,
        Wm[cur], Wm[nxt], Wh[nxt], Wl[nxt], WTh[nxt], WTl[nxt],
        nullptr, nullptr, 0);
    cur = nxt;
  }

  if (Xb) k_big_bf<<<2048, 256, 0, stream>>>(Xb, Wh[cur], out);
  else    k_big<<<2048, 256, 0, stream>>>(X, Wh[cur], out);
}